// Round 4
// baseline (815.374 us; speedup 1.0000x reference)
//
#include <hip/hip_runtime.h>

typedef unsigned short u16;
typedef unsigned long long u64;
typedef __bf16  bf16x8 __attribute__((ext_vector_type(8)));
typedef float   f32x4  __attribute__((ext_vector_type(4)));

#define N_ROWS 1500000
#define S_SEG  16384
#define ROWS_PB 32
#define TILES_PB 15
#define GRID_MAIN 3125      // 3125 * 15 * 32 = 1,500,000 exactly

#define XS_LD  72           // 64 bf16 cols + 8 pad, XOR-swizzled
#define H1B_LD 264          // 256 cols (br0 | br1) + 8 pad, bf16, XOR-swizzled

// hardware RNE f32->bf16 (v_cvt_pk_bf16_f32 on gfx950)
__device__ __forceinline__ u16 f2bf(float f) {
    union { __bf16 h; u16 u; } cv;
    cv.h = (__bf16)f;
    return cv.u;
}

// barrier WITHOUT vmcnt drain: LDS visibility only; global loads/atomics stay in flight
__device__ __forceinline__ void barrier_nodrain() {
    asm volatile("s_waitcnt lgkmcnt(0)" ::: "memory");
    __builtin_amdgcn_s_barrier();
}

// ---------------- zero the fp32 segment accumulators ----------------
__global__ void zero_ws_kernel(float* p, int n4) {
    int i = blockIdx.x * 256 + threadIdx.x;
    if (i < n4) reinterpret_cast<float4*>(p)[i] = make_float4(0.f, 0.f, 0.f, 0.f);
}

// ------- transpose + fp32->bf16 convert the 4 big-GEMM weight matrices -------
__global__ void transpose_weights(const float* __restrict__ w0, const float* __restrict__ w1,
                                  const float* __restrict__ r0, const float* __restrict__ r1,
                                  u16* __restrict__ w0T, u16* __restrict__ w1T,
                                  u16* __restrict__ r0T, u16* __restrict__ r1T) {
    int idx = blockIdx.x * 256 + threadIdx.x;     // 0 .. 24576
    if (idx < 8192) {
        int o = idx >> 6, k = idx & 63;
        w0T[o * 64 + k] = f2bf(w0[k * 128 + o]);
    } else if (idx < 12288) {
        int t = idx - 8192; int o = t >> 7, k = t & 127;
        w1T[o * 128 + k] = f2bf(w1[k * 32 + o]);
    } else if (idx < 20480) {
        int t = idx - 12288; int o = t >> 6, k = t & 63;
        r0T[o * 64 + k] = f2bf(r0[k * 128 + o]);
    } else if (idx < 24576) {
        int t = idx - 20480; int o = t >> 7, k = t & 127;
        r1T[o * 128 + k] = f2bf(r1[k * 32 + o]);
    }
}

// ---------------- main: persistent 15-tile blocks ----------------
// Swapped GEMM1: mfma(W-frag as A, x-frag as B) -> lane holds 4 consecutive h1
// cols for one x-row -> packed ushort4 LDS writes. GEMM2 unswapped; its f32x4
// accumulators feed an in-register segment reduction (no h2 LDS, no 3rd barrier).
// Raw barriers (lgkmcnt only) keep x-prefetch + atomics in flight.
// LDS: xs dbl 9216 + h1s 16896 + ids 256 = 26368 B.
__global__ __launch_bounds__(256, 4) void main_mlp_seg(
    const float* __restrict__ x, const int* __restrict__ seg_ids,
    const u16* __restrict__ w0T, const float* __restrict__ b0a,
    const u16* __restrict__ w1T, const float* __restrict__ b1a,
    const u16* __restrict__ r0T, const float* __restrict__ rb0,
    const u16* __restrict__ r1T, const float* __restrict__ rb1,
    float* __restrict__ seg_out, float* __restrict__ rseg_out)
{
    __shared__ u16 xs [2][ROWS_PB * XS_LD];
    __shared__ u16 h1s[ROWS_PB * H1B_LD];
    __shared__ int s_ids[2][ROWS_PB];

    const int tid  = threadIdx.x;
    const int wid  = tid >> 6, lane = tid & 63;
    const int m = lane & 15, q = lane >> 4;
    const int swm = (m & 7) << 3;                 // u16-unit XOR swizzle for rows == m (mod 8)
    const size_t row0 = (size_t)blockIdx.x * (TILES_PB * ROWS_PB);

    // ---- hoist all GEMM weights + biases into registers (forced residency) ----
    bf16x8 wA[2][2][2];     // [br][ct][ks] GEMM1 A-frag: W0T[n0+m][k]
    f32x4  bias0v[2][2];    // bias for cols n0 + q*4 + i
    #pragma unroll
    for (int br = 0; br < 2; ++br) {
        const u16*   W0 = br ? r0T : w0T;
        const float* B0 = br ? rb0 : b0a;
        #pragma unroll
        for (int ct = 0; ct < 2; ++ct) {
            int n0 = (2 * wid + ct) * 16;
            #pragma unroll
            for (int ks = 0; ks < 2; ++ks)
                wA[br][ct][ks] = *reinterpret_cast<const bf16x8*>(W0 + (n0 + m) * 64 + ks * 32 + q * 8);
            bias0v[br][ct] = *reinterpret_cast<const f32x4*>(B0 + n0 + q * 4);
        }
    }
    const int brw = wid >> 1, rtw = wid & 1;     // GEMM2: wave -> (branch, row-half)
    const u16*   W1 = brw ? r1T : w1T;
    const float* B1 = brw ? rb1 : b1a;
    bf16x8 wB[2][4];        // [ct][ks] GEMM2 B-frag: W1T[ct*16+m][k]
    float  bz1[2];
    #pragma unroll
    for (int ct = 0; ct < 2; ++ct) {
        #pragma unroll
        for (int ks = 0; ks < 4; ++ks)
            wB[ct][ks] = *reinterpret_cast<const bf16x8*>(W1 + (ct * 16 + m) * 128 + ks * 32 + q * 8);
        bz1[ct] = B1[ct * 16 + m];
    }
    // keep-alive: weights/biases become asm-defined -> compiler cannot re-load per tile
    asm volatile("" :
        "+v"(wA[0][0][0]), "+v"(wA[0][0][1]), "+v"(wA[0][1][0]), "+v"(wA[0][1][1]),
        "+v"(wA[1][0][0]), "+v"(wA[1][0][1]), "+v"(wA[1][1][0]), "+v"(wA[1][1][1]));
    asm volatile("" :
        "+v"(wB[0][0]), "+v"(wB[0][1]), "+v"(wB[0][2]), "+v"(wB[0][3]),
        "+v"(wB[1][0]), "+v"(wB[1][1]), "+v"(wB[1][2]), "+v"(wB[1][3]));
    asm volatile("" :
        "+v"(bias0v[0][0]), "+v"(bias0v[0][1]), "+v"(bias0v[1][0]), "+v"(bias0v[1][1]));

    // ---- x staging geometry: thread -> rows {sr, sr+16}, float4 col sc4 ----
    const int sr = tid >> 4, sc4 = tid & 15;
    const int sws = (sr & 7) << 3;
    const int xw0 = sr * XS_LD        + ((sc4 * 4) ^ sws);
    const int xw1 = (sr + 16) * XS_LD + ((sc4 * 4) ^ sws);
    const float* xb = x + (row0 + sr) * 64 + sc4 * 4;

    // ---- prologue: tile 0 load+commit, tile 1 issue ----
    {
        float4 v0 = *reinterpret_cast<const float4*>(xb);
        float4 v1 = *reinterpret_cast<const float4*>(xb + 1024);
        ushort4 p0, p1;
        p0.x = f2bf(v0.x); p0.y = f2bf(v0.y); p0.z = f2bf(v0.z); p0.w = f2bf(v0.w);
        p1.x = f2bf(v1.x); p1.y = f2bf(v1.y); p1.z = f2bf(v1.z); p1.w = f2bf(v1.w);
        *reinterpret_cast<ushort4*>(&xs[0][xw0]) = p0;
        *reinterpret_cast<ushort4*>(&xs[0][xw1]) = p1;
        if (tid < ROWS_PB) s_ids[0][tid] = seg_ids[row0 + tid];
    }
    float4 xr0 = *reinterpret_cast<const float4*>(xb + 2048);
    float4 xr1 = *reinterpret_cast<const float4*>(xb + 2048 + 1024);
    int idr = 0;
    if (tid < ROWS_PB) idr = seg_ids[row0 + ROWS_PB + tid];
    barrier_nodrain();

    // ---- cross-tile pending segment accumulator (per lane; q==0 lanes flush) ----
    int   pid = -1;
    float p0a = 0.f, p1a = 0.f;
    bool  have = false;
    float* __restrict__ sp = brw ? rseg_out : seg_out;

    int cur = 0;
    #pragma unroll 1
    for (int t = 0; t < TILES_PB; ++t) {
        const int nxt = cur ^ 1;
        // ---- Phase A: commit t+1 to LDS, issue t+2, GEMM1 (swapped) ----
        if (t + 1 < TILES_PB) {
            ushort4 pk0, pk1;
            pk0.x = f2bf(xr0.x); pk0.y = f2bf(xr0.y); pk0.z = f2bf(xr0.z); pk0.w = f2bf(xr0.w);
            pk1.x = f2bf(xr1.x); pk1.y = f2bf(xr1.y); pk1.z = f2bf(xr1.z); pk1.w = f2bf(xr1.w);
            *reinterpret_cast<ushort4*>(&xs[nxt][xw0]) = pk0;
            *reinterpret_cast<ushort4*>(&xs[nxt][xw1]) = pk1;
            if (tid < ROWS_PB) s_ids[nxt][tid] = idr;
        }
        if (t + 2 < TILES_PB) {
            const float* px = xb + (size_t)(t + 2) * 2048;
            xr0 = *reinterpret_cast<const float4*>(px);
            xr1 = *reinterpret_cast<const float4*>(px + 1024);
            if (tid < ROWS_PB) idr = seg_ids[row0 + (size_t)(t + 2) * ROWS_PB + tid];
        }
        #pragma unroll
        for (int rt = 0; rt < 2; ++rt) {
            bf16x8 a0 = *reinterpret_cast<const bf16x8*>(
                &xs[cur][(rt * 16 + m) * XS_LD + ((q * 8) ^ swm)]);
            bf16x8 a1 = *reinterpret_cast<const bf16x8*>(
                &xs[cur][(rt * 16 + m) * XS_LD + ((32 + q * 8) ^ swm)]);
            #pragma unroll
            for (int br = 0; br < 2; ++br) {
                #pragma unroll
                for (int ct = 0; ct < 2; ++ct) {
                    f32x4 acc = bias0v[br][ct];
                    acc = __builtin_amdgcn_mfma_f32_16x16x32_bf16(wA[br][ct][0], a0, acc, 0, 0, 0);
                    acc = __builtin_amdgcn_mfma_f32_16x16x32_bf16(wA[br][ct][1], a1, acc, 0, 0, 0);
                    ushort4 pk;
                    pk.x = f2bf(fmaxf(acc[0], 0.f));
                    pk.y = f2bf(fmaxf(acc[1], 0.f));
                    pk.z = f2bf(fmaxf(acc[2], 0.f));
                    pk.w = f2bf(fmaxf(acc[3], 0.f));
                    int col = br * 128 + (2 * wid + ct) * 16 + q * 4;
                    *reinterpret_cast<ushort4*>(
                        &h1s[(rt * 16 + m) * H1B_LD + (col ^ swm)]) = pk;
                }
            }
        }
        barrier_nodrain();   // h1 visible; prefetch loads NOT drained

        // ---- Phase B: GEMM2 + in-register segment reduction ----
        {
            const int* ids = s_ids[cur];
            int l31 = (lane < 32) ? lane : 0;
            int ida = ids[l31];
            int idb = ids[(l31 > 0) ? (l31 - 1) : 0];
            u64 bmask = __ballot(lane > 0 && lane < 32 && ida != idb);

            bf16x8 a[4];
            #pragma unroll
            for (int ks = 0; ks < 4; ++ks)
                a[ks] = *reinterpret_cast<const bf16x8*>(
                    &h1s[(rtw * 16 + m) * H1B_LD + ((brw * 128 + ks * 32 + q * 8) ^ swm)]);
            f32x4 acc0 = {bz1[0], bz1[0], bz1[0], bz1[0]};
            f32x4 acc1 = {bz1[1], bz1[1], bz1[1], bz1[1]};
            #pragma unroll
            for (int ks = 0; ks < 4; ++ks) {
                acc0 = __builtin_amdgcn_mfma_f32_16x16x32_bf16(a[ks], wB[0][ks], acc0, 0, 0, 0);
                acc1 = __builtin_amdgcn_mfma_f32_16x16x32_bf16(a[ks], wB[1][ks], acc1, 0, 0, 0);
            }

            // sorted-run loop (wave-uniform); relu applied per element before sum
            int start = 0;
            while (start < 32) {
                u64 above = bmask & (~0ull << (start + 1));
                int end = above ? (int)__builtin_ctzll(above) : 32;
                int sid = ids[start];
                if (sid != pid) {
                    if (have && q == 0) {
                        atomicAdd(&sp[pid * 32 + m],      p0a);
                        atomicAdd(&sp[pid * 32 + 16 + m], p1a);
                    }
                    pid = sid; p0a = 0.f; p1a = 0.f; have = false;
                }
                float s0 = 0.f, s1 = 0.f;
                #pragma unroll
                for (int i = 0; i < 4; ++i) {
                    int row = rtw * 16 + q * 4 + i;
                    bool in = (row >= start) && (row < end);
                    s0 += in ? fmaxf(acc0[i], 0.f) : 0.f;
                    s1 += in ? fmaxf(acc1[i], 0.f) : 0.f;
                }
                s0 += __shfl_xor(s0, 16); s0 += __shfl_xor(s0, 32);
                s1 += __shfl_xor(s1, 16); s1 += __shfl_xor(s1, 32);
                if (end > rtw * 16 && start < rtw * 16 + 16) {
                    p0a += s0; p1a += s1; have = true;
                }
                start = end;
            }
        }
        barrier_nodrain();   // h1/xs/ids reads done before next overwrite
        cur = nxt;
    }
    // final flush
    if (have && q == 0) {
        atomicAdd(&sp[pid * 32 + m],      p0a);
        atomicAdd(&sp[pid * 32 + 16 + m], p1a);
    }
}

// ---------------- per-segment heads + cost MLP + policy (fp32 in, fp32 out) ----------------
__global__ __launch_bounds__(256) void heads_kernel(
    const float* __restrict__ seg, const float* __restrict__ rseg,
    const float* __restrict__ fwd0_w, const float* __restrict__ fwd0_b,
    const float* __restrict__ fwd1_w, const float* __restrict__ fwd1_b,
    const float* __restrict__ com0_w, const float* __restrict__ com0_b,
    const float* __restrict__ com1_w, const float* __restrict__ com1_b,
    const float* __restrict__ bwd0_w, const float* __restrict__ bwd0_b,
    const float* __restrict__ bwd1_w, const float* __restrict__ bwd1_b,
    const float* __restrict__ cost0_w, const float* __restrict__ cost0_b,
    const float* __restrict__ cost1_w, const float* __restrict__ cost1_b,
    const float* __restrict__ pol_w, const float* __restrict__ pol_b,
    float* __restrict__ out)
{
    __shared__ float s_seg[4][32];
    __shared__ float s_rseg[4][32];
    __shared__ float s_c0[4][64];
    const int tid = threadIdx.x, wid = tid >> 6, lane = tid & 63;
    const int s = blockIdx.x * 4 + wid;

    if (lane < 32) {
        s_seg[wid][lane]  = seg[s * 32 + lane];
        s_rseg[wid][lane] = rseg[s * 32 + lane];
    }
    __syncthreads();

    const float* w0s[3] = {fwd0_w, com0_w, bwd0_w};
    const float* b0s[3] = {fwd0_b, com0_b, bwd0_b};
    const float* w1s[3] = {fwd1_w, com1_w, bwd1_w};
    const float* b1s[3] = {fwd1_b, com1_b, bwd1_b};
    float costs[3];
    #pragma unroll
    for (int hh = 0; hh < 3; ++hh) {
        float t = 0.f;
        #pragma unroll
        for (int k = 0; k < 32; ++k)
            t = fmaf(s_seg[wid][k], w0s[hh][k * 64 + lane], t);
        t = fmaxf(t + b0s[hh][lane], 0.f);
        float red = t * w1s[hh][lane];
        red += __shfl_down(red, 32);
        red += __shfl_down(red, 16);
        red += __shfl_down(red, 8);
        red += __shfl_down(red, 4);
        red += __shfl_down(red, 2);
        red += __shfl_down(red, 1);
        costs[hh] = __shfl(red, 0) + b1s[hh][0];
    }

    float c0 = costs[0] * cost0_w[lane] +
               costs[1] * cost0_w[64 + lane] +
               costs[2] * cost0_w[128 + lane] + cost0_b[lane];
    c0 = fmaxf(c0, 0.f);
    s_c0[wid][lane] = c0;
    __syncthreads();

    int kk = lane & 31;
    float c1 = 0.f;
    #pragma unroll 8
    for (int j = 0; j < 64; ++j)
        c1 = fmaf(s_c0[wid][j], cost1_w[j * 32 + kk], c1);
    c1 = fmaxf(c1 + cost1_b[kk], 0.f);

    float p = 0.f;
    if (lane < 32)
        p = s_rseg[wid][lane] * pol_w[lane] + c1 * pol_w[32 + lane];
    p += __shfl_down(p, 32);
    p += __shfl_down(p, 16);
    p += __shfl_down(p, 8);
    p += __shfl_down(p, 4);
    p += __shfl_down(p, 2);
    p += __shfl_down(p, 1);
    if (lane == 0) out[s] = p + pol_b[0];    // fp32 output
}

extern "C" void kernel_launch(void* const* d_in, const int* in_sizes, int n_in,
                              void* d_out, int out_size, void* d_ws, size_t ws_size,
                              hipStream_t stream) {
    const float* x       = (const float*)d_in[0];
    const int*   seg_ids = (const int*)d_in[1];
    const float* tfc0_w = (const float*)d_in[4];
    const float* tfc0_b = (const float*)d_in[5];
    const float* tfc1_w = (const float*)d_in[6];
    const float* tfc1_b = (const float*)d_in[7];
    const float* fwd0_w = (const float*)d_in[8];
    const float* fwd0_b = (const float*)d_in[9];
    const float* fwd1_w = (const float*)d_in[10];
    const float* fwd1_b = (const float*)d_in[11];
    const float* com0_w = (const float*)d_in[12];
    const float* com0_b = (const float*)d_in[13];
    const float* com1_w = (const float*)d_in[14];
    const float* com1_b = (const float*)d_in[15];
    const float* bwd0_w = (const float*)d_in[16];
    const float* bwd0_b = (const float*)d_in[17];
    const float* bwd1_w = (const float*)d_in[18];
    const float* bwd1_b = (const float*)d_in[19];
    const float* rl0_w  = (const float*)d_in[20];
    const float* rl0_b  = (const float*)d_in[21];
    const float* rl1_w  = (const float*)d_in[22];
    const float* rl1_b  = (const float*)d_in[23];
    const float* cost0_w = (const float*)d_in[24];
    const float* cost0_b = (const float*)d_in[25];
    const float* cost1_w = (const float*)d_in[26];
    const float* cost1_b = (const float*)d_in[27];
    const float* pol_w   = (const float*)d_in[28];
    const float* pol_b   = (const float*)d_in[29];

    char* ws = (char*)d_ws;
    const size_t seg_bytes = (size_t)S_SEG * 32 * sizeof(float);   // 2 MB each
    float* seg  = (float*)ws;
    float* rseg = (float*)(ws + seg_bytes);
    u16* w0T = (u16*)(ws + 2 * seg_bytes);
    u16* w1T = w0T + 128 * 64;
    u16* r0T = w1T + 32 * 128;
    u16* r1T = r0T + 128 * 64;

    int n4 = (int)(2 * seg_bytes / 16);
    zero_ws_kernel<<<(n4 + 255) / 256, 256, 0, stream>>>(seg, n4);
    transpose_weights<<<96, 256, 0, stream>>>(tfc0_w, tfc1_w, rl0_w, rl1_w,
                                              w0T, w1T, r0T, r1T);
    main_mlp_seg<<<GRID_MAIN, 256, 0, stream>>>(
        x, seg_ids, w0T, tfc0_b, w1T, tfc1_b, r0T, rl0_b, r1T, rl1_b, seg, rseg);
    heads_kernel<<<S_SEG / 4, 256, 0, stream>>>(
        seg, rseg,
        fwd0_w, fwd0_b, fwd1_w, fwd1_b,
        com0_w, com0_b, com1_w, com1_b,
        bwd0_w, bwd0_b, bwd1_w, bwd1_b,
        cost0_w, cost0_b, cost1_w, cost1_b,
        pol_w, pol_b, (float*)d_out);
}

// Round 5
// 627.303 us; speedup vs baseline: 1.2998x; 1.2998x over previous
//
#include <hip/hip_runtime.h>

typedef unsigned short u16;
typedef unsigned long long u64;
typedef __bf16  bf16x8 __attribute__((ext_vector_type(8)));
typedef float   f32x4  __attribute__((ext_vector_type(4)));

#define N_ROWS 1500000
#define S_SEG  16384
#define ROWS_PB 32
#define TILES_PB 15
#define GRID_MAIN 3125      // 3125 * 15 * 32 = 1,500,000 exactly

#define XS_LD  72           // 64 bf16 cols + 8 pad (plain padding, no swizzle)
#define H1B_LD 264          // 256 cols (br0 | br1) + 8 pad, bf16

// hardware RNE f32->bf16 (v_cvt_pk_bf16_f32 on gfx950)
__device__ __forceinline__ u16 f2bf(float f) {
    union { __bf16 h; u16 u; } cv;
    cv.h = (__bf16)f;
    return cv.u;
}

// barrier WITHOUT vmcnt drain: LDS visibility only; global loads/atomics stay in flight
__device__ __forceinline__ void barrier_nodrain() {
    asm volatile("s_waitcnt lgkmcnt(0)" ::: "memory");
    __builtin_amdgcn_s_barrier();
}

// ---------------- zero the fp32 segment accumulators ----------------
__global__ void zero_ws_kernel(float* p, int n4) {
    int i = blockIdx.x * 256 + threadIdx.x;
    if (i < n4) reinterpret_cast<float4*>(p)[i] = make_float4(0.f, 0.f, 0.f, 0.f);
}

// ------- transpose + fp32->bf16 convert the 4 big-GEMM weight matrices -------
__global__ void transpose_weights(const float* __restrict__ w0, const float* __restrict__ w1,
                                  const float* __restrict__ r0, const float* __restrict__ r1,
                                  u16* __restrict__ w0T, u16* __restrict__ w1T,
                                  u16* __restrict__ r0T, u16* __restrict__ r1T) {
    int idx = blockIdx.x * 256 + threadIdx.x;     // 0 .. 24576
    if (idx < 8192) {
        int o = idx >> 6, k = idx & 63;
        w0T[o * 64 + k] = f2bf(w0[k * 128 + o]);
    } else if (idx < 12288) {
        int t = idx - 8192; int o = t >> 7, k = t & 127;
        w1T[o * 128 + k] = f2bf(w1[k * 32 + o]);
    } else if (idx < 20480) {
        int t = idx - 12288; int o = t >> 6, k = t & 63;
        r0T[o * 64 + k] = f2bf(r0[k * 128 + o]);
    } else if (idx < 24576) {
        int t = idx - 20480; int o = t >> 7, k = t & 127;
        r1T[o * 128 + k] = f2bf(r1[k * 32 + o]);
    }
}

// ---------------- main: persistent 15-tile blocks, 8 waves, 2 nodrain barriers/tile ----------------
// Swapped GEMM1: mfma(W-frag, x-frag) -> lane holds 4 consecutive h1 cols -> packed ushort4 writes.
// GEMM2 accumulators feed an in-register sorted-run segment reduction (no h2 LDS, no 3rd barrier).
// 8 waves halve per-wave weight state (wA 16 + wB 16 VGPR) so everything fits the 64-VGPR tier:
// no rematerialization (R3 lesson), no spill (R4 lesson). Biases live in LDS.
// LDS: xs dbl 9216 + h1s 16896 + ids 256 + bias 1280 = 27648 B; 4 blocks/CU (wave-slot cap).
__global__ __launch_bounds__(512, 4) void main_mlp_seg(
    const float* __restrict__ x, const int* __restrict__ seg_ids,
    const u16* __restrict__ w0T, const float* __restrict__ b0a,
    const u16* __restrict__ w1T, const float* __restrict__ b1a,
    const u16* __restrict__ r0T, const float* __restrict__ rb0,
    const u16* __restrict__ r1T, const float* __restrict__ rb1,
    float* __restrict__ seg_out, float* __restrict__ rseg_out)
{
    __shared__ u16   xs [2][ROWS_PB * XS_LD];
    __shared__ u16   h1s[ROWS_PB * H1B_LD];
    __shared__ int   s_ids[2][ROWS_PB];
    __shared__ float bls0[256];   // GEMM1 bias: [br0 0-127 | br1 0-127]
    __shared__ float bls1[64];    // GEMM2 bias: [br0 0-31  | br1 0-31]

    const int tid = threadIdx.x;
    const int wid = tid >> 6, lane = tid & 63;
    const int m = lane & 15, q = lane >> 4;
    const size_t row0 = (size_t)blockIdx.x * (TILES_PB * ROWS_PB);

    // GEMM1: wave -> branch brA = wid>>2, two 16-col tiles (wid&3)*2 + {0,1}
    const int brA = wid >> 2;
    const u16* W0 = brA ? r0T : w0T;
    // GEMM2: wave -> (brw, rtw, ctw)
    const int brw = wid >> 2, rtw = (wid >> 1) & 1, ctw = wid & 1;
    const u16* W1 = brw ? r1T : w1T;

    // ---- per-wave weight fragments (small enough to stay resident at 64 VGPR) ----
    bf16x8 wA[2][2];          // [ct][ks]
    #pragma unroll
    for (int c = 0; c < 2; ++c) {
        int n0 = ((wid & 3) * 2 + c) * 16;
        wA[c][0] = *reinterpret_cast<const bf16x8*>(W0 + (n0 + m) * 64 + q * 8);
        wA[c][1] = *reinterpret_cast<const bf16x8*>(W0 + (n0 + m) * 64 + 32 + q * 8);
    }
    bf16x8 wB[4];             // [ks]
    #pragma unroll
    for (int ks = 0; ks < 4; ++ks)
        wB[ks] = *reinterpret_cast<const bf16x8*>(W1 + (ctw * 16 + m) * 128 + ks * 32 + q * 8);

    // ---- stage biases to LDS ----
    if (tid < 128)      bls0[tid] = b0a[tid];
    else if (tid < 256) bls0[tid] = rb0[tid - 128];
    else if (tid < 288) bls1[tid - 256] = b1a[tid - 256];
    else if (tid < 320) bls1[tid - 256] = rb1[tid - 288];

    // ---- x staging: one float4 per thread (512 threads = 32 rows x 16 float4) ----
    const int sr = tid >> 4, sc4 = tid & 15;
    const float* xb = x + (row0 + sr) * 64 + sc4 * 4;
    const int xw = sr * XS_LD + sc4 * 4;

    // ---- prologue: tile 0 commit, tile 1 in regs ----
    {
        float4 v = *reinterpret_cast<const float4*>(xb);
        ushort4 pk;
        pk.x = f2bf(v.x); pk.y = f2bf(v.y); pk.z = f2bf(v.z); pk.w = f2bf(v.w);
        *reinterpret_cast<ushort4*>(&xs[0][xw]) = pk;
        if (tid < ROWS_PB) s_ids[0][tid] = seg_ids[row0 + tid];
    }
    float4 xr = *reinterpret_cast<const float4*>(xb + 2048);
    int idr = (tid < ROWS_PB) ? seg_ids[row0 + ROWS_PB + tid] : 0;
    barrier_nodrain();

    // ---- cross-tile pending segment accumulator ----
    int   pid = -1;
    float pacc = 0.f;
    bool  have = false;
    float* __restrict__ sp = brw ? rseg_out : seg_out;
    const int colg = ctw * 16 + m;

    int cur = 0;
    #pragma unroll 1
    for (int t = 0; t < TILES_PB; ++t) {
        const int nxt = cur ^ 1;
        // ---- Phase A: commit t+1, issue t+2, GEMM1 (swapped) ----
        if (t + 1 < TILES_PB) {
            ushort4 pk;
            pk.x = f2bf(xr.x); pk.y = f2bf(xr.y); pk.z = f2bf(xr.z); pk.w = f2bf(xr.w);
            *reinterpret_cast<ushort4*>(&xs[nxt][xw]) = pk;
            if (tid < ROWS_PB) s_ids[nxt][tid] = idr;
        }
        if (t + 2 < TILES_PB) {
            xr = *reinterpret_cast<const float4*>(xb + (size_t)(t + 2) * 2048);
            if (tid < ROWS_PB) idr = seg_ids[row0 + (size_t)(t + 2) * ROWS_PB + tid];
        }
        #pragma unroll
        for (int rt = 0; rt < 2; ++rt) {
            bf16x8 a0 = *reinterpret_cast<const bf16x8*>(&xs[cur][(rt * 16 + m) * XS_LD + q * 8]);
            bf16x8 a1 = *reinterpret_cast<const bf16x8*>(&xs[cur][(rt * 16 + m) * XS_LD + 32 + q * 8]);
            #pragma unroll
            for (int c = 0; c < 2; ++c) {
                int n0 = ((wid & 3) * 2 + c) * 16;
                f32x4 acc = *reinterpret_cast<const f32x4*>(&bls0[brA * 128 + n0 + q * 4]);
                acc = __builtin_amdgcn_mfma_f32_16x16x32_bf16(wA[c][0], a0, acc, 0, 0, 0);
                acc = __builtin_amdgcn_mfma_f32_16x16x32_bf16(wA[c][1], a1, acc, 0, 0, 0);
                ushort4 pk;
                pk.x = f2bf(fmaxf(acc[0], 0.f));
                pk.y = f2bf(fmaxf(acc[1], 0.f));
                pk.z = f2bf(fmaxf(acc[2], 0.f));
                pk.w = f2bf(fmaxf(acc[3], 0.f));
                *reinterpret_cast<ushort4*>(
                    &h1s[(rt * 16 + m) * H1B_LD + brA * 128 + n0 + q * 4]) = pk;
            }
        }
        barrier_nodrain();   // h1 visible; x prefetch + atomics stay in flight

        // ---- Phase B: GEMM2 + in-register sorted-run segment reduction ----
        {
            const int* ids = s_ids[cur];
            int l31 = (lane < 32) ? lane : 0;
            int ida = ids[l31];
            int idb = ids[l31 ? l31 - 1 : 0];
            u64 bmask = __ballot(lane > 0 && lane < 32 && ida != idb);

            bf16x8 a[4];
            #pragma unroll
            for (int ks = 0; ks < 4; ++ks)
                a[ks] = *reinterpret_cast<const bf16x8*>(
                    &h1s[(rtw * 16 + m) * H1B_LD + brw * 128 + ks * 32 + q * 8]);
            float bz = bls1[brw * 32 + colg];
            f32x4 acc = {bz, bz, bz, bz};
            #pragma unroll
            for (int ks = 0; ks < 4; ++ks)
                acc = __builtin_amdgcn_mfma_f32_16x16x32_bf16(a[ks], wB[ks], acc, 0, 0, 0);

            int start = 0;
            while (start < 32) {
                u64 above = bmask & (~0ull << (start + 1));
                int end = above ? (int)__builtin_ctzll(above) : 32;
                int sid = ids[start];
                if (sid != pid) {
                    if (have && q == 0) atomicAdd(&sp[pid * 32 + colg], pacc);
                    pid = sid; pacc = 0.f; have = false;
                }
                float s = 0.f;
                #pragma unroll
                for (int i = 0; i < 4; ++i) {
                    int row = rtw * 16 + q * 4 + i;
                    s += (row >= start && row < end) ? fmaxf(acc[i], 0.f) : 0.f;
                }
                s += __shfl_xor(s, 16);
                s += __shfl_xor(s, 32);
                if (end > rtw * 16 && start < rtw * 16 + 16) { pacc += s; have = true; }
                start = end;
            }
        }
        barrier_nodrain();   // h1/xs/ids reads done before next tile overwrites
        cur = nxt;
    }
    // final flush
    if (have && q == 0) atomicAdd(&sp[pid * 32 + colg], pacc);
}

// ---------------- per-segment heads + cost MLP + policy (fp32 in, fp32 out) ----------------
__global__ __launch_bounds__(256) void heads_kernel(
    const float* __restrict__ seg, const float* __restrict__ rseg,
    const float* __restrict__ fwd0_w, const float* __restrict__ fwd0_b,
    const float* __restrict__ fwd1_w, const float* __restrict__ fwd1_b,
    const float* __restrict__ com0_w, const float* __restrict__ com0_b,
    const float* __restrict__ com1_w, const float* __restrict__ com1_b,
    const float* __restrict__ bwd0_w, const float* __restrict__ bwd0_b,
    const float* __restrict__ bwd1_w, const float* __restrict__ bwd1_b,
    const float* __restrict__ cost0_w, const float* __restrict__ cost0_b,
    const float* __restrict__ cost1_w, const float* __restrict__ cost1_b,
    const float* __restrict__ pol_w, const float* __restrict__ pol_b,
    float* __restrict__ out)
{
    __shared__ float s_seg[4][32];
    __shared__ float s_rseg[4][32];
    __shared__ float s_c0[4][64];
    const int tid = threadIdx.x, wid = tid >> 6, lane = tid & 63;
    const int s = blockIdx.x * 4 + wid;

    if (lane < 32) {
        s_seg[wid][lane]  = seg[s * 32 + lane];
        s_rseg[wid][lane] = rseg[s * 32 + lane];
    }
    __syncthreads();

    const float* w0s[3] = {fwd0_w, com0_w, bwd0_w};
    const float* b0s[3] = {fwd0_b, com0_b, bwd0_b};
    const float* w1s[3] = {fwd1_w, com1_w, bwd1_w};
    const float* b1s[3] = {fwd1_b, com1_b, bwd1_b};
    float costs[3];
    #pragma unroll
    for (int hh = 0; hh < 3; ++hh) {
        float t = 0.f;
        #pragma unroll
        for (int k = 0; k < 32; ++k)
            t = fmaf(s_seg[wid][k], w0s[hh][k * 64 + lane], t);
        t = fmaxf(t + b0s[hh][lane], 0.f);
        float red = t * w1s[hh][lane];
        red += __shfl_down(red, 32);
        red += __shfl_down(red, 16);
        red += __shfl_down(red, 8);
        red += __shfl_down(red, 4);
        red += __shfl_down(red, 2);
        red += __shfl_down(red, 1);
        costs[hh] = __shfl(red, 0) + b1s[hh][0];
    }

    float c0 = costs[0] * cost0_w[lane] +
               costs[1] * cost0_w[64 + lane] +
               costs[2] * cost0_w[128 + lane] + cost0_b[lane];
    c0 = fmaxf(c0, 0.f);
    s_c0[wid][lane] = c0;
    __syncthreads();

    int kk = lane & 31;
    float c1 = 0.f;
    #pragma unroll 8
    for (int j = 0; j < 64; ++j)
        c1 = fmaf(s_c0[wid][j], cost1_w[j * 32 + kk], c1);
    c1 = fmaxf(c1 + cost1_b[kk], 0.f);

    float p = 0.f;
    if (lane < 32)
        p = s_rseg[wid][lane] * pol_w[lane] + c1 * pol_w[32 + lane];
    p += __shfl_down(p, 32);
    p += __shfl_down(p, 16);
    p += __shfl_down(p, 8);
    p += __shfl_down(p, 4);
    p += __shfl_down(p, 2);
    p += __shfl_down(p, 1);
    if (lane == 0) out[s] = p + pol_b[0];    // fp32 output
}

extern "C" void kernel_launch(void* const* d_in, const int* in_sizes, int n_in,
                              void* d_out, int out_size, void* d_ws, size_t ws_size,
                              hipStream_t stream) {
    const float* x       = (const float*)d_in[0];
    const int*   seg_ids = (const int*)d_in[1];
    const float* tfc0_w = (const float*)d_in[4];
    const float* tfc0_b = (const float*)d_in[5];
    const float* tfc1_w = (const float*)d_in[6];
    const float* tfc1_b = (const float*)d_in[7];
    const float* fwd0_w = (const float*)d_in[8];
    const float* fwd0_b = (const float*)d_in[9];
    const float* fwd1_w = (const float*)d_in[10];
    const float* fwd1_b = (const float*)d_in[11];
    const float* com0_w = (const float*)d_in[12];
    const float* com0_b = (const float*)d_in[13];
    const float* com1_w = (const float*)d_in[14];
    const float* com1_b = (const float*)d_in[15];
    const float* bwd0_w = (const float*)d_in[16];
    const float* bwd0_b = (const float*)d_in[17];
    const float* bwd1_w = (const float*)d_in[18];
    const float* bwd1_b = (const float*)d_in[19];
    const float* rl0_w  = (const float*)d_in[20];
    const float* rl0_b  = (const float*)d_in[21];
    const float* rl1_w  = (const float*)d_in[22];
    const float* rl1_b  = (const float*)d_in[23];
    const float* cost0_w = (const float*)d_in[24];
    const float* cost0_b = (const float*)d_in[25];
    const float* cost1_w = (const float*)d_in[26];
    const float* cost1_b = (const float*)d_in[27];
    const float* pol_w   = (const float*)d_in[28];
    const float* pol_b   = (const float*)d_in[29];

    char* ws = (char*)d_ws;
    const size_t seg_bytes = (size_t)S_SEG * 32 * sizeof(float);   // 2 MB each
    float* seg  = (float*)ws;
    float* rseg = (float*)(ws + seg_bytes);
    u16* w0T = (u16*)(ws + 2 * seg_bytes);
    u16* w1T = w0T + 128 * 64;
    u16* r0T = w1T + 32 * 128;
    u16* r1T = r0T + 128 * 64;

    int n4 = (int)(2 * seg_bytes / 16);
    zero_ws_kernel<<<(n4 + 255) / 256, 256, 0, stream>>>(seg, n4);
    transpose_weights<<<96, 256, 0, stream>>>(tfc0_w, tfc1_w, rl0_w, rl1_w,
                                              w0T, w1T, r0T, r1T);
    main_mlp_seg<<<GRID_MAIN, 512, 0, stream>>>(
        x, seg_ids, w0T, tfc0_b, w1T, tfc1_b, r0T, rl0_b, r1T, rl1_b, seg, rseg);
    heads_kernel<<<S_SEG / 4, 256, 0, stream>>>(
        seg, rseg,
        fwd0_w, fwd0_b, fwd1_w, fwd1_b,
        com0_w, com0_b, com1_w, com1_b,
        bwd0_w, bwd0_b, bwd1_w, bwd1_b,
        cost0_w, cost0_b, cost1_w, cost1_b,
        pol_w, pol_b, (float*)d_out);
}

// Round 6
// 619.347 us; speedup vs baseline: 1.3165x; 1.0128x over previous
//
#include <hip/hip_runtime.h>

typedef unsigned short u16;
typedef unsigned long long u64;
typedef __bf16  bf16x8 __attribute__((ext_vector_type(8)));
typedef float   f32x4  __attribute__((ext_vector_type(4)));

#define N_ROWS 1500000
#define S_SEG  16384
#define ROWS_PB 32
#define TILES_PB 15
#define GRID_MAIN 3125      // 3125 * 15 * 32 = 1,500,000 exactly

#define XS_LD  72           // 64 bf16 cols + 8 pad
#define H1B_LD 264          // 256 cols (br0 | br1) + 8 pad, bf16

// hardware RNE f32->bf16 (v_cvt_pk_bf16_f32 on gfx950)
__device__ __forceinline__ u16 f2bf(float f) {
    union { __bf16 h; u16 u; } cv;
    cv.h = (__bf16)f;
    return cv.u;
}

// barrier WITHOUT vmcnt drain: LDS visibility only; global loads/atomics stay in flight
__device__ __forceinline__ void barrier_nodrain() {
    asm volatile("s_waitcnt lgkmcnt(0)" ::: "memory");
    __builtin_amdgcn_s_barrier();
}

// ---------------- prep: zero seg accumulators + transpose/convert weights ----------------
__global__ void prep_kernel(float* p, int n4,
                            const float* __restrict__ w0, const float* __restrict__ w1,
                            const float* __restrict__ r0, const float* __restrict__ r1,
                            u16* __restrict__ w0T, u16* __restrict__ w1T,
                            u16* __restrict__ r0T, u16* __restrict__ r1T) {
    if (blockIdx.x < 1024) {
        int i = blockIdx.x * 256 + threadIdx.x;
        if (i < n4) reinterpret_cast<float4*>(p)[i] = make_float4(0.f, 0.f, 0.f, 0.f);
        return;
    }
    int idx = (blockIdx.x - 1024) * 256 + threadIdx.x;     // 0 .. 24576
    if (idx < 8192) {
        int o = idx >> 6, k = idx & 63;
        w0T[o * 64 + k] = f2bf(w0[k * 128 + o]);
    } else if (idx < 12288) {
        int t = idx - 8192; int o = t >> 7, k = t & 127;
        w1T[o * 128 + k] = f2bf(w1[k * 32 + o]);
    } else if (idx < 20480) {
        int t = idx - 12288; int o = t >> 6, k = t & 63;
        r0T[o * 64 + k] = f2bf(r0[k * 128 + o]);
    } else if (idx < 24576) {
        int t = idx - 20480; int o = t >> 7, k = t & 127;
        r1T[o * 128 + k] = f2bf(r1[k * 32 + o]);
    }
}

// ---------------- main: persistent 15-tile blocks, 8 waves, software-pipelined ----------------
// Iter i: GEMM1(tile i) -> h1s[i&1]  ||  GEMM2(tile i-1) <- h1s[(i-1)&1]  ||  stage tile i+1/i+2.
// ONE nodrain barrier per iteration: all LDS hazards are on opposite buffer parities
// (h1 dbuf, xs dbuf, ids mod-4 ring with write-ahead +1 / read-behind -1).
// Swapped GEMM1 (mfma(W,x)): lane holds 4 consecutive h1 cols -> packed ushort4 writes.
// GEMM2 accumulators feed the in-register sorted-run segment reduction (no h2 LDS).
// LDS: xs dbl 9216 + h1 dbl 33792 + ids 512 = 43520 B -> 3 blocks/CU.
__global__ __launch_bounds__(512, 4) void main_mlp_seg(
    const float* __restrict__ x, const int* __restrict__ seg_ids,
    const u16* __restrict__ w0T, const float* __restrict__ b0a,
    const u16* __restrict__ w1T, const float* __restrict__ b1a,
    const u16* __restrict__ r0T, const float* __restrict__ rb0,
    const u16* __restrict__ r1T, const float* __restrict__ rb1,
    float* __restrict__ seg_out, float* __restrict__ rseg_out)
{
    __shared__ u16 xs [2][ROWS_PB * XS_LD];
    __shared__ u16 h1s[2][ROWS_PB * H1B_LD];
    __shared__ int s_ids[4][ROWS_PB];

    const int tid = threadIdx.x;
    const int wid = tid >> 6, lane = tid & 63;
    const int m = lane & 15, q = lane >> 4;
    const size_t row0 = (size_t)blockIdx.x * (TILES_PB * ROWS_PB);

    // GEMM1: wave -> branch brA = wid>>2, two 16-col tiles (wid&3)*2 + {0,1}
    const int brA = wid >> 2;
    const u16*   W0  = brA ? r0T : w0T;
    const float* B0g = brA ? rb0 : b0a;
    // GEMM2: wave -> (brw, rtw, ctw)
    const int brw = wid >> 2, rtw = (wid >> 1) & 1, ctw = wid & 1;
    const u16*   W1  = brw ? r1T : w1T;
    const float* B1g = brw ? rb1 : b1a;

    // ---- per-wave weight fragments + biases in registers ----
    bf16x8 wA[2][2];          // [ct][ks]
    f32x4  b0v[2];
    #pragma unroll
    for (int c = 0; c < 2; ++c) {
        int n0 = ((wid & 3) * 2 + c) * 16;
        wA[c][0] = *reinterpret_cast<const bf16x8*>(W0 + (n0 + m) * 64 + q * 8);
        wA[c][1] = *reinterpret_cast<const bf16x8*>(W0 + (n0 + m) * 64 + 32 + q * 8);
        b0v[c]   = *reinterpret_cast<const f32x4*>(B0g + n0 + q * 4);
    }
    bf16x8 wB[4];             // [ks]
    #pragma unroll
    for (int ks = 0; ks < 4; ++ks)
        wB[ks] = *reinterpret_cast<const bf16x8*>(W1 + (ctw * 16 + m) * 128 + ks * 32 + q * 8);
    const int colg = ctw * 16 + m;
    const float bz = B1g[colg];

    // ---- x staging: one float4 per thread (512 threads = 32 rows x 16 float4) ----
    const int sr = tid >> 4, sc4 = tid & 15;
    const float* xb = x + (row0 + sr) * 64 + sc4 * 4;
    const int xw = sr * XS_LD + sc4 * 4;

    // ---- prologue: tile 0 commit, tile 1 in regs ----
    {
        float4 v = *reinterpret_cast<const float4*>(xb);
        ushort4 pk;
        pk.x = f2bf(v.x); pk.y = f2bf(v.y); pk.z = f2bf(v.z); pk.w = f2bf(v.w);
        *reinterpret_cast<ushort4*>(&xs[0][xw]) = pk;
        if (tid < ROWS_PB) s_ids[0][tid] = seg_ids[row0 + tid];
    }
    float4 xr = *reinterpret_cast<const float4*>(xb + 2048);
    int idr = (tid < ROWS_PB) ? seg_ids[row0 + ROWS_PB + tid] : 0;
    barrier_nodrain();

    // ---- cross-tile pending segment accumulator ----
    int   pid = -1;
    float pacc = 0.f;
    bool  have = false;
    float* __restrict__ sp = brw ? rseg_out : seg_out;

    #pragma unroll 1
    for (int i = 0; i <= TILES_PB; ++i) {
        if (i < TILES_PB) {
            // commit tile i+1, issue tile i+2
            if (i + 1 < TILES_PB) {
                ushort4 pk;
                pk.x = f2bf(xr.x); pk.y = f2bf(xr.y); pk.z = f2bf(xr.z); pk.w = f2bf(xr.w);
                *reinterpret_cast<ushort4*>(&xs[(i + 1) & 1][xw]) = pk;
                if (tid < ROWS_PB) s_ids[(i + 1) & 3][tid] = idr;
            }
            if (i + 2 < TILES_PB) {
                xr = *reinterpret_cast<const float4*>(xb + (size_t)(i + 2) * 2048);
                if (tid < ROWS_PB) idr = seg_ids[row0 + (size_t)(i + 2) * ROWS_PB + tid];
            }
            // ---- GEMM1(tile i), swapped ----
            const u16* xsc = xs[i & 1];
            u16* h1d = h1s[i & 1];
            #pragma unroll
            for (int rt = 0; rt < 2; ++rt) {
                bf16x8 a0 = *reinterpret_cast<const bf16x8*>(&xsc[(rt * 16 + m) * XS_LD + q * 8]);
                bf16x8 a1 = *reinterpret_cast<const bf16x8*>(&xsc[(rt * 16 + m) * XS_LD + 32 + q * 8]);
                #pragma unroll
                for (int c = 0; c < 2; ++c) {
                    int n0 = ((wid & 3) * 2 + c) * 16;
                    f32x4 acc = b0v[c];
                    acc = __builtin_amdgcn_mfma_f32_16x16x32_bf16(wA[c][0], a0, acc, 0, 0, 0);
                    acc = __builtin_amdgcn_mfma_f32_16x16x32_bf16(wA[c][1], a1, acc, 0, 0, 0);
                    ushort4 pk;
                    pk.x = f2bf(fmaxf(acc[0], 0.f));
                    pk.y = f2bf(fmaxf(acc[1], 0.f));
                    pk.z = f2bf(fmaxf(acc[2], 0.f));
                    pk.w = f2bf(fmaxf(acc[3], 0.f));
                    *reinterpret_cast<ushort4*>(
                        &h1d[(rt * 16 + m) * H1B_LD + brA * 128 + n0 + q * 4]) = pk;
                }
            }
        }
        if (i > 0) {
            // ---- GEMM2(tile i-1) + in-register sorted-run segment reduction ----
            const int pt = i - 1;
            const int* ids = s_ids[pt & 3];
            const u16* h1c = h1s[pt & 1];
            int l31 = (lane < 32) ? lane : 0;
            int ida = ids[l31];
            int idb = ids[l31 ? l31 - 1 : 0];
            u64 bmask = __ballot(lane > 0 && lane < 32 && ida != idb);

            bf16x8 a[4];
            #pragma unroll
            for (int ks = 0; ks < 4; ++ks)
                a[ks] = *reinterpret_cast<const bf16x8*>(
                    &h1c[(rtw * 16 + m) * H1B_LD + brw * 128 + ks * 32 + q * 8]);
            f32x4 acc = {bz, bz, bz, bz};
            #pragma unroll
            for (int ks = 0; ks < 4; ++ks)
                acc = __builtin_amdgcn_mfma_f32_16x16x32_bf16(a[ks], wB[ks], acc, 0, 0, 0);

            int start = 0;
            while (start < 32) {
                u64 above = bmask & (~0ull << (start + 1));
                int end = above ? (int)__builtin_ctzll(above) : 32;
                int sid = ids[start];
                if (sid != pid) {
                    if (have && q == 0) atomicAdd(&sp[pid * 32 + colg], pacc);
                    pid = sid; pacc = 0.f; have = false;
                }
                float s = 0.f;
                #pragma unroll
                for (int ii = 0; ii < 4; ++ii) {
                    int row = rtw * 16 + q * 4 + ii;
                    s += (row >= start && row < end) ? fmaxf(acc[ii], 0.f) : 0.f;
                }
                s += __shfl_xor(s, 16);
                s += __shfl_xor(s, 32);
                if (end > rtw * 16 && start < rtw * 16 + 16) { pacc += s; have = true; }
                start = end;
            }
        }
        if (i < TILES_PB) barrier_nodrain();
    }
    // final flush
    if (have && q == 0) atomicAdd(&sp[pid * 32 + colg], pacc);
}

// ---------------- per-segment heads + cost MLP + policy (fp32 in, fp32 out) ----------------
__global__ __launch_bounds__(256) void heads_kernel(
    const float* __restrict__ seg, const float* __restrict__ rseg,
    const float* __restrict__ fwd0_w, const float* __restrict__ fwd0_b,
    const float* __restrict__ fwd1_w, const float* __restrict__ fwd1_b,
    const float* __restrict__ com0_w, const float* __restrict__ com0_b,
    const float* __restrict__ com1_w, const float* __restrict__ com1_b,
    const float* __restrict__ bwd0_w, const float* __restrict__ bwd0_b,
    const float* __restrict__ bwd1_w, const float* __restrict__ bwd1_b,
    const float* __restrict__ cost0_w, const float* __restrict__ cost0_b,
    const float* __restrict__ cost1_w, const float* __restrict__ cost1_b,
    const float* __restrict__ pol_w, const float* __restrict__ pol_b,
    float* __restrict__ out)
{
    __shared__ float s_seg[4][32];
    __shared__ float s_rseg[4][32];
    __shared__ float s_c0[4][64];
    const int tid = threadIdx.x, wid = tid >> 6, lane = tid & 63;
    const int s = blockIdx.x * 4 + wid;

    if (lane < 32) {
        s_seg[wid][lane]  = seg[s * 32 + lane];
        s_rseg[wid][lane] = rseg[s * 32 + lane];
    }
    __syncthreads();

    const float* w0s[3] = {fwd0_w, com0_w, bwd0_w};
    const float* b0s[3] = {fwd0_b, com0_b, bwd0_b};
    const float* w1s[3] = {fwd1_w, com1_w, bwd1_w};
    const float* b1s[3] = {fwd1_b, com1_b, bwd1_b};
    float costs[3];
    #pragma unroll
    for (int hh = 0; hh < 3; ++hh) {
        float t = 0.f;
        #pragma unroll
        for (int k = 0; k < 32; ++k)
            t = fmaf(s_seg[wid][k], w0s[hh][k * 64 + lane], t);
        t = fmaxf(t + b0s[hh][lane], 0.f);
        float red = t * w1s[hh][lane];
        red += __shfl_down(red, 32);
        red += __shfl_down(red, 16);
        red += __shfl_down(red, 8);
        red += __shfl_down(red, 4);
        red += __shfl_down(red, 2);
        red += __shfl_down(red, 1);
        costs[hh] = __shfl(red, 0) + b1s[hh][0];
    }

    float c0 = costs[0] * cost0_w[lane] +
               costs[1] * cost0_w[64 + lane] +
               costs[2] * cost0_w[128 + lane] + cost0_b[lane];
    c0 = fmaxf(c0, 0.f);
    s_c0[wid][lane] = c0;
    __syncthreads();

    int kk = lane & 31;
    float c1 = 0.f;
    #pragma unroll 8
    for (int j = 0; j < 64; ++j)
        c1 = fmaf(s_c0[wid][j], cost1_w[j * 32 + kk], c1);
    c1 = fmaxf(c1 + cost1_b[kk], 0.f);

    float p = 0.f;
    if (lane < 32)
        p = s_rseg[wid][lane] * pol_w[lane] + c1 * pol_w[32 + lane];
    p += __shfl_down(p, 32);
    p += __shfl_down(p, 16);
    p += __shfl_down(p, 8);
    p += __shfl_down(p, 4);
    p += __shfl_down(p, 2);
    p += __shfl_down(p, 1);
    if (lane == 0) out[s] = p + pol_b[0];    // fp32 output
}

extern "C" void kernel_launch(void* const* d_in, const int* in_sizes, int n_in,
                              void* d_out, int out_size, void* d_ws, size_t ws_size,
                              hipStream_t stream) {
    const float* x       = (const float*)d_in[0];
    const int*   seg_ids = (const int*)d_in[1];
    const float* tfc0_w = (const float*)d_in[4];
    const float* tfc0_b = (const float*)d_in[5];
    const float* tfc1_w = (const float*)d_in[6];
    const float* tfc1_b = (const float*)d_in[7];
    const float* fwd0_w = (const float*)d_in[8];
    const float* fwd0_b = (const float*)d_in[9];
    const float* fwd1_w = (const float*)d_in[10];
    const float* fwd1_b = (const float*)d_in[11];
    const float* com0_w = (const float*)d_in[12];
    const float* com0_b = (const float*)d_in[13];
    const float* com1_w = (const float*)d_in[14];
    const float* com1_b = (const float*)d_in[15];
    const float* bwd0_w = (const float*)d_in[16];
    const float* bwd0_b = (const float*)d_in[17];
    const float* bwd1_w = (const float*)d_in[18];
    const float* bwd1_b = (const float*)d_in[19];
    const float* rl0_w  = (const float*)d_in[20];
    const float* rl0_b  = (const float*)d_in[21];
    const float* rl1_w  = (const float*)d_in[22];
    const float* rl1_b  = (const float*)d_in[23];
    const float* cost0_w = (const float*)d_in[24];
    const float* cost0_b = (const float*)d_in[25];
    const float* cost1_w = (const float*)d_in[26];
    const float* cost1_b = (const float*)d_in[27];
    const float* pol_w   = (const float*)d_in[28];
    const float* pol_b   = (const float*)d_in[29];

    char* ws = (char*)d_ws;
    const size_t seg_bytes = (size_t)S_SEG * 32 * sizeof(float);   // 2 MB each
    float* seg  = (float*)ws;
    float* rseg = (float*)(ws + seg_bytes);
    u16* w0T = (u16*)(ws + 2 * seg_bytes);
    u16* w1T = w0T + 128 * 64;
    u16* r0T = w1T + 32 * 128;
    u16* r1T = r0T + 128 * 64;

    int n4 = (int)(2 * seg_bytes / 16);
    prep_kernel<<<1024 + 96, 256, 0, stream>>>(seg, n4,
                                               tfc0_w, tfc1_w, rl0_w, rl1_w,
                                               w0T, w1T, r0T, r1T);
    main_mlp_seg<<<GRID_MAIN, 512, 0, stream>>>(
        x, seg_ids, w0T, tfc0_b, w1T, tfc1_b, r0T, rl0_b, r1T, rl1_b, seg, rseg);
    heads_kernel<<<S_SEG / 4, 256, 0, stream>>>(
        seg, rseg,
        fwd0_w, fwd0_b, fwd1_w, fwd1_b,
        com0_w, com0_b, com1_w, com1_b,
        bwd0_w, bwd0_b, bwd1_w, bwd1_b,
        cost0_w, cost0_b, cost1_w, cost1_b,
        pol_w, pol_b, (float*)d_out);
}